// Round 1
// baseline (102.036 us; speedup 1.0000x reference)
//
#include <hip/hip_runtime.h>

// ROIAlign 1D on (bs=8, ch=256, T=512) fp32, rois (N=2048, 3), P=16, S=4.
// Output (N, ch, P) fp32.
//
// Layout: 1 block per ROI, 256 threads. tid -> p = tid&15, cg = tid>>4.
// Loop j over 16 channel groups: c = cg + 16*j.
// Store address = n*4096 + 256*j + (cg*16 + p) = contiguous per wave. Coalesced.
// Sampling weights (t0, wl, wh) per (p,s) computed once per thread, reused
// over all 16 channels. Invalid samples get zero weights (no divergence).
// Interp: t0 = min(x_low, T-2), w = xc - t0 -> exact also at the T-1 clamp
// (w becomes 1.0, selecting f[T-1]); both taps adjacent -> dwordx2-mergeable.

#define T_DIM 512
#define CH    256
#define P_DIM 16
#define S_RAT 4

__global__ __launch_bounds__(256) void roialign_kernel(
    const float* __restrict__ feat,   // (8, 256, 512)
    const float* __restrict__ rois,   // (2048, 3)
    float* __restrict__ out)          // (2048, 256, 16)
{
    const int n   = blockIdx.x;
    const int tid = threadIdx.x;
    const int p   = tid & 15;
    const int cg  = tid >> 4;   // 0..15

    const float bf    = rois[n * 3 + 0];
    const float start = rois[n * 3 + 1];
    const float end   = rois[n * 3 + 2];
    const int   b     = (int)bf;

    const float roi_len = fmaxf(end - start, 1.0f);
    const float bin     = roi_len * (1.0f / P_DIM);

    // Per-sample metadata for this thread's bin p.
    int   t0[S_RAT];
    float wl[S_RAT], wh[S_RAT];
#pragma unroll
    for (int s = 0; s < S_RAT; ++s) {
        float x     = start + ((float)p + ((float)s + 0.5f) * (1.0f / S_RAT)) * bin;
        bool  valid = (x >= -1.0f) && (x <= (float)T_DIM);
        float xc    = fminf(fmaxf(x, 0.0f), (float)(T_DIM - 1));
        int   xl    = (int)floorf(xc);
        int   t     = xl < (T_DIM - 2) ? xl : (T_DIM - 2);
        float w     = xc - (float)t;
        float scale = valid ? (1.0f / S_RAT) : 0.0f;
        t0[s] = t;
        wl[s] = (1.0f - w) * scale;
        wh[s] = w * scale;
    }

    const float* base = feat + (size_t)b * CH * T_DIM;
    float*       outn = out + (size_t)n * CH * P_DIM;

#pragma unroll 4
    for (int j = 0; j < 16; ++j) {
        const int    c   = cg + j * 16;
        const float* row = base + c * T_DIM;
        float acc = 0.0f;
#pragma unroll
        for (int s = 0; s < S_RAT; ++s) {
            float vx = row[t0[s]];
            float vy = row[t0[s] + 1];
            acc = fmaf(vx, wl[s], acc);
            acc = fmaf(vy, wh[s], acc);
        }
        outn[c * P_DIM + p] = acc;
    }
}

extern "C" void kernel_launch(void* const* d_in, const int* in_sizes, int n_in,
                              void* d_out, int out_size, void* d_ws, size_t ws_size,
                              hipStream_t stream) {
    const float* feat = (const float*)d_in[0];   // (8,256,512)
    const float* rois = (const float*)d_in[1];   // (2048,3)
    // d_in[2] = feature_dim (16), d_in[3] = ratio (4) — compile-time constants here.
    float* out = (float*)d_out;                  // (2048,256,16)

    const int N = in_sizes[1] / 3;               // 2048
    roialign_kernel<<<dim3(N), dim3(256), 0, stream>>>(feat, rois, out);
}

// Round 2
// 92.588 us; speedup vs baseline: 1.1020x; 1.1020x over previous
//
#include <hip/hip_runtime.h>

// ROIAlign 1D: feat (8,256,512) fp32, rois (2048,3), P=16, S=4 -> out (2048,256,16).
//
// Round-1 kernel was L1-transaction-bound: gather addresses scattered along T
// within each wave (~48 L1 lines touched per load inst) -> 102 us vs ~6 us floor.
//
// Fix: two-phase.
//   Phase 1: transpose feat (b, c, t) -> featT (b, t, c) in d_ws (4 MB).
//   Phase 2: one WAVE per ROI (64 lanes x 4 channels via float4). For each of
//            the 64 samples (p,s), all lanes load featT[b, t, 4*lane .. +4] --
//            256 consecutive floats per wave = fully coalesced 1 KB loads.
//            Sample metadata (t0, wl, wh) is wave-uniform, recomputed per lane
//            (cheap VALU, hides under L1/L2 read throughput).
// Interp: t0 = min(floor(xc), T-2), w = xc - t0 (exact at the T-1 clamp, w=1).
// Invalid samples (x outside [-1, T]) fold into zero weights - no divergence.

#define T_DIM 512
#define CH    256
#define P_DIM 16
#define S_RAT 4
#define ROIS_PER_BLOCK 4

__global__ __launch_bounds__(256) void transpose_kernel(
    const float* __restrict__ feat,   // (8, 256, 512)
    float*       __restrict__ featT)  // (8, 512, 256)
{
    __shared__ float tile[32][33];    // +1 pad: no bank conflicts
    const int t0 = blockIdx.x * 32;
    const int c0 = blockIdx.y * 32;
    const int b  = blockIdx.z;
    const int tx = threadIdx.x;       // 0..31
    const int ty = threadIdx.y;       // 0..7

    const float* src = feat + ((size_t)b * CH + c0) * T_DIM + t0;
#pragma unroll
    for (int k = 0; k < 4; ++k)
        tile[ty + k * 8][tx] = src[(ty + k * 8) * T_DIM + tx];   // coalesced in t
    __syncthreads();
    float* dst = featT + ((size_t)b * T_DIM + t0) * CH + c0;
#pragma unroll
    for (int k = 0; k < 4; ++k)
        dst[(ty + k * 8) * CH + tx] = tile[tx][ty + k * 8];      // coalesced in c
}

__global__ __launch_bounds__(256) void roialign_coalesced_kernel(
    const float* __restrict__ featT,  // (8, 512, 256)
    const float* __restrict__ rois,   // (2048, 3)
    float* __restrict__ out)          // (2048, 256, 16)
{
    const int tid  = threadIdx.x;
    const int lane = tid & 63;        // channel quad: channels 4*lane .. 4*lane+3
    const int r    = tid >> 6;        // ROI within block (one wave per ROI)
    const int n    = blockIdx.x * ROIS_PER_BLOCK + r;

    const float bf    = rois[n * 3 + 0];
    const float start = rois[n * 3 + 1];
    const float end   = rois[n * 3 + 2];
    const int   b     = (int)bf;
    const float bin   = fmaxf(end - start, 1.0f) * (1.0f / P_DIM);

    const float4* base4 = (const float4*)(featT + (size_t)b * T_DIM * CH) + lane;

    float acc[P_DIM][4];
#pragma unroll
    for (int p = 0; p < P_DIM; ++p)
        acc[p][0] = acc[p][1] = acc[p][2] = acc[p][3] = 0.0f;

#pragma unroll
    for (int p = 0; p < P_DIM; ++p) {
#pragma unroll
        for (int s = 0; s < S_RAT; ++s) {
            float x     = fmaf((float)p + ((float)s + 0.5f) * (1.0f / S_RAT), bin, start);
            bool  valid = (x >= -1.0f) && (x <= (float)T_DIM);
            float xc    = fminf(fmaxf(x, 0.0f), (float)(T_DIM - 1));
            int   xl    = (int)floorf(xc);
            int   t     = xl < (T_DIM - 2) ? xl : (T_DIM - 2);
            float w     = xc - (float)t;
            float scale = valid ? (1.0f / S_RAT) : 0.0f;
            float wl    = (1.0f - w) * scale;
            float wh    = w * scale;
            float4 v0 = base4[(size_t)t * (CH / 4)];        // coalesced: 64 lanes x 16 B
            float4 v1 = base4[(size_t)(t + 1) * (CH / 4)];
            acc[p][0] = fmaf(v0.x, wl, fmaf(v1.x, wh, acc[p][0]));
            acc[p][1] = fmaf(v0.y, wl, fmaf(v1.y, wh, acc[p][1]));
            acc[p][2] = fmaf(v0.z, wl, fmaf(v1.z, wh, acc[p][2]));
            acc[p][3] = fmaf(v0.w, wl, fmaf(v1.w, wh, acc[p][3]));
        }
    }

    // Store: thread owns channels c = 4*lane + i, each with 16 contiguous bins.
    float* outp = out + (size_t)n * (CH * P_DIM) + (size_t)(lane * 4) * P_DIM;
#pragma unroll
    for (int i = 0; i < 4; ++i) {
#pragma unroll
        for (int k = 0; k < 4; ++k) {
            float4 v = make_float4(acc[4 * k + 0][i], acc[4 * k + 1][i],
                                   acc[4 * k + 2][i], acc[4 * k + 3][i]);
            *(float4*)(outp + i * P_DIM + 4 * k) = v;
        }
    }
}

// Fallback (round-1 kernel) if ws is too small for the transpose.
__global__ __launch_bounds__(256) void roialign_fallback_kernel(
    const float* __restrict__ feat, const float* __restrict__ rois,
    float* __restrict__ out)
{
    const int n   = blockIdx.x;
    const int tid = threadIdx.x;
    const int p   = tid & 15;
    const int cg  = tid >> 4;

    const float bf    = rois[n * 3 + 0];
    const float start = rois[n * 3 + 1];
    const float end   = rois[n * 3 + 2];
    const int   b     = (int)bf;
    const float bin   = fmaxf(end - start, 1.0f) * (1.0f / P_DIM);

    int   t0[S_RAT]; float wl[S_RAT], wh[S_RAT];
#pragma unroll
    for (int s = 0; s < S_RAT; ++s) {
        float x     = start + ((float)p + ((float)s + 0.5f) * (1.0f / S_RAT)) * bin;
        bool  valid = (x >= -1.0f) && (x <= (float)T_DIM);
        float xc    = fminf(fmaxf(x, 0.0f), (float)(T_DIM - 1));
        int   xl    = (int)floorf(xc);
        int   t     = xl < (T_DIM - 2) ? xl : (T_DIM - 2);
        float w     = xc - (float)t;
        float scale = valid ? (1.0f / S_RAT) : 0.0f;
        t0[s] = t; wl[s] = (1.0f - w) * scale; wh[s] = w * scale;
    }
    const float* base = feat + (size_t)b * CH * T_DIM;
    float*       outn = out + (size_t)n * CH * P_DIM;
#pragma unroll 4
    for (int j = 0; j < 16; ++j) {
        const int c = cg + j * 16;
        const float* row = base + c * T_DIM;
        float acc = 0.0f;
#pragma unroll
        for (int s = 0; s < S_RAT; ++s) {
            acc = fmaf(row[t0[s]], wl[s], acc);
            acc = fmaf(row[t0[s] + 1], wh[s], acc);
        }
        outn[c * P_DIM + p] = acc;
    }
}

extern "C" void kernel_launch(void* const* d_in, const int* in_sizes, int n_in,
                              void* d_out, int out_size, void* d_ws, size_t ws_size,
                              hipStream_t stream) {
    const float* feat = (const float*)d_in[0];   // (8,256,512)
    const float* rois = (const float*)d_in[1];   // (2048,3)
    float* out = (float*)d_out;                  // (2048,256,16)
    const int N = in_sizes[1] / 3;               // 2048

    const size_t featT_bytes = (size_t)8 * T_DIM * CH * sizeof(float);  // 4 MB
    if (ws_size >= featT_bytes) {
        float* featT = (float*)d_ws;
        transpose_kernel<<<dim3(T_DIM / 32, CH / 32, 8), dim3(32, 8), 0, stream>>>(feat, featT);
        roialign_coalesced_kernel<<<dim3(N / ROIS_PER_BLOCK), dim3(256), 0, stream>>>(featT, rois, out);
    } else {
        roialign_fallback_kernel<<<dim3(N), dim3(256), 0, stream>>>(feat, rois, out);
    }
}

// Round 3
// 84.496 us; speedup vs baseline: 1.2076x; 1.0958x over previous
//
#include <hip/hip_runtime.h>

// ROIAlign 1D: feat (8,256,512) fp32, rois (2048,3), P=16, S=4 -> out (2048,256,16).
//
// Round-2 post-mortem: the featT-gather kernel moved 268 MB of read requests
// (2048 ROIs x 128 x 1KB wave-loads). featT (4MB) ~ L2 size, thrashed by the
// 33.5 MB streaming out-writes -> reads flowed at L3/HBM rate:
// 268 MB / 6.3 TB/s = 42 us ~= measured ~40 us (dur_us also carries ~50 us of
// harness re-poison fills, per rocprof: no dispatch > 47 us).
//
// This version reuses feat via LDS instead of re-reading per ROI:
//   grid = (32 channel-tiles, 8 ROI-slices, 8 batches), block = 256.
//   Each block: stage feat[b, ct*8 .. +8, :] (16 KB) into LDS once, compact
//   the ROIs of its slice with bidx==b into an LDS list, then thread (c,p)
//   computes out[n, c, p] for each listed ROI from the LDS tile.
// Read traffic: ~20 MB (tiles re-read RSPLIT x) vs 268 MB before.
// New ceiling: 1.05M wave ds_read_b32 x 5.8cyc / 256 CU ~= 10 us (LDS-bound);
// VALU (~5 us) and HBM writes (33.5 MB ~ 5.3 us) hide under it.
//
// LDS tile stride 516 floats (mult of 4 -> aligned float4 staging writes;
// read bank = (4c + t) % 32 spreads channels; same-(p,s) same-address reads
// across the 8 channel-threads broadcast for free).

#define T_DIM 512
#define CH    256
#define P_DIM 16
#define S_RAT 4
#define CTILE 8
#define NCT   (CH / CTILE)     // 32
#define RSPLIT 8
#define MAXSL  256             // ROI-slice length = 2048 / RSPLIT
#define TSTRIDE 516            // LDS tile row stride (floats)

__global__ __launch_bounds__(256) void roialign_lds_kernel(
    const float* __restrict__ feat,   // (8, 256, 512)
    const float* __restrict__ rois,   // (N, 3)
    float* __restrict__ out,          // (N, 256, 16)
    int N)
{
    __shared__ float tile[CTILE * TSTRIDE];   // 16.5 KB
    __shared__ float s_start[MAXSL];
    __shared__ float s_end[MAXSL];
    __shared__ int   s_idx[MAXSL];
    __shared__ int   s_cnt;

    const int ct  = blockIdx.x;   // channel tile 0..31
    const int r   = blockIdx.y;   // ROI slice 0..RSPLIT-1
    const int b   = blockIdx.z;   // batch 0..7
    const int tid = threadIdx.x;

    if (tid == 0) s_cnt = 0;

    // --- Stage feat tile: 8 rows x 512 floats, coalesced float4 loads. ---
    {
        const int c = tid >> 5;        // 0..7
        const int q = tid & 31;        // 0..31
        const float4* src = (const float4*)(feat + ((size_t)b * CH + ct * CTILE + c) * T_DIM);
        float4* drow = (float4*)&tile[c * TSTRIDE];   // TSTRIDE % 4 == 0 -> aligned
#pragma unroll
        for (int k = 0; k < 4; ++k)
            drow[q + 32 * k] = src[q + 32 * k];
    }
    __syncthreads();   // covers s_cnt init too

    // --- Compact this slice's matching ROIs into LDS. ---
    {
        const int lo = r * MAXSL;
        const int i  = lo + tid;
        if (i < N && i < lo + MAXSL) {
            float bf = rois[3 * i];
            if ((int)bf == b) {
                int pos = atomicAdd(&s_cnt, 1);
                s_idx[pos]   = i;
                s_start[pos] = rois[3 * i + 1];
                s_end[pos]   = rois[3 * i + 2];
            }
        }
    }
    __syncthreads();
    const int cnt = s_cnt;

    // --- Process: two 128-thread groups, each one ROI per iteration. ---
    const int g    = tid >> 7;        // 0,1
    const int t128 = tid & 127;
    const int c    = t128 >> 4;       // 0..7
    const int p    = t128 & 15;       // 0..15
    const float* trow = &tile[c * TSTRIDE];
    const int c_out = (ct * CTILE + c) * P_DIM + p;

    for (int i = g; i < cnt; i += 2) {
        const int   n     = s_idx[i];
        const float start = s_start[i];
        const float end   = s_end[i];
        const float bin   = fmaxf(end - start, 1.0f) * (1.0f / P_DIM);

        float acc = 0.0f;
#pragma unroll
        for (int s = 0; s < S_RAT; ++s) {
            float x     = fmaf((float)p + ((float)s + 0.5f) * (1.0f / S_RAT), bin, start);
            bool  valid = (x >= -1.0f) && (x <= (float)T_DIM);
            float xc    = fminf(fmaxf(x, 0.0f), (float)(T_DIM - 1));
            int   t     = (int)floorf(xc);
            t = t < (T_DIM - 2) ? t : (T_DIM - 2);
            float w     = xc - (float)t;
            float scale = valid ? (1.0f / S_RAT) : 0.0f;
            acc = fmaf(trow[t],     (1.0f - w) * scale, acc);
            acc = fmaf(trow[t + 1], w * scale,          acc);
        }
        // Wave lanes (c 0..3 | p 0..15) -> 64 consecutive floats: coalesced.
        out[(size_t)n * (CH * P_DIM) + c_out] = acc;
    }
}

extern "C" void kernel_launch(void* const* d_in, const int* in_sizes, int n_in,
                              void* d_out, int out_size, void* d_ws, size_t ws_size,
                              hipStream_t stream) {
    const float* feat = (const float*)d_in[0];   // (8,256,512)
    const float* rois = (const float*)d_in[1];   // (N,3)
    float* out = (float*)d_out;                  // (N,256,16)
    const int N = in_sizes[1] / 3;               // 2048

    dim3 grid(NCT, RSPLIT, 8);                   // 2048 blocks
    roialign_lds_kernel<<<grid, dim3(256), 0, stream>>>(feat, rois, out, N);
}

// Round 4
// 83.198 us; speedup vs baseline: 1.2264x; 1.0156x over previous
//
#include <hip/hip_runtime.h>

// ROIAlign 1D: feat (8,256,512) fp32, rois (2048,3), P=16, S=4 -> out (2048,256,16).
//
// R3 post-mortem: dur_us carries ~48 us of harness re-poison (268 MB d_ws fill
// at 42 us + 33.5 MB out fill); kernel itself ~36 us vs 15 us model. Two causes:
//  (1) TSTRIDE=516 == 4 (mod 32): bank = (4c+t)%32; common bin strides (2/4/8)
//      are multiples of 2/4 -> 4-to-8-way LDS conflicts (2.94x at 8-way, m136).
//  (2) Full valid/clamp metadata recomputed per channel-thread (~70 VALU/ROI).
//
// This round:
//  - TSTRIDE=517 (== 5 mod 32, odd): bank = (5c+t)%32. For bin=2/4/8 the 5c
//    channel offsets land in distinct residues mod 4 -> all 32 banks 2-way
//    (2-way is free). Staging via b32 writes (row base no longer 16B-aligned).
//  - Inputs guarantee start in [0,511), end <= 512 -> every sample x in [0,512):
//    'valid' always true, low clamp never binds. Drop both. t = min(trunc(xc),510),
//    w = xc - t is exact at the high clamp (w=1 selects f[511]).
//  - Hoist per-(p,s) sample offsets; unroll ROI loop x2 for LDS ILP.
//
// Cost model per CU (8 blocks/CU at 19.6 KB LDS): LDS 512 wave-b32/block x 5.8 cyc
// x ~1.05 conflict = 25 K cyc ~= 10.4 us; VALU ~5 us, HBM writes 5.4 us (overlap).
// Kernel ~13 us -> dur ~60-63 us.

#define T_DIM 512
#define CH    256
#define P_DIM 16
#define S_RAT 4
#define CTILE 8
#define NCT   (CH / CTILE)     // 32
#define RSPLIT 8
#define MAXSL  256             // ROI-slice length = 2048 / RSPLIT
#define TSTRIDE 517            // LDS tile row stride: odd, == 5 (mod 32)

__global__ __launch_bounds__(256) void roialign_lds_kernel(
    const float* __restrict__ feat,   // (8, 256, 512)
    const float* __restrict__ rois,   // (N, 3)
    float* __restrict__ out,          // (N, 256, 16)
    int N)
{
    __shared__ float tile[CTILE * TSTRIDE];   // 16.2 KB
    __shared__ float s_start[MAXSL];
    __shared__ float s_end[MAXSL];
    __shared__ int   s_idx[MAXSL];
    __shared__ int   s_cnt;

    const int ct  = blockIdx.x;   // channel tile 0..31
    const int r   = blockIdx.y;   // ROI slice 0..RSPLIT-1
    const int b   = blockIdx.z;   // batch 0..7
    const int tid = threadIdx.x;

    if (tid == 0) s_cnt = 0;

    // --- Stage feat tile: 8 rows x 512 floats. float4 global loads, b32 LDS writes. ---
    {
        const int c = tid >> 5;        // 0..7
        const int q = tid & 31;        // 0..31
        const float4* src = (const float4*)(feat + ((size_t)b * CH + ct * CTILE + c) * T_DIM);
        float* drow = &tile[c * TSTRIDE];
#pragma unroll
        for (int k = 0; k < 4; ++k) {
            float4 v = src[q + 32 * k];
            const int o = 4 * (q + 32 * k);
            drow[o + 0] = v.x; drow[o + 1] = v.y;
            drow[o + 2] = v.z; drow[o + 3] = v.w;
        }
    }
    __syncthreads();   // covers s_cnt init too

    // --- Compact this slice's matching ROIs into LDS. ---
    {
        const int i = r * MAXSL + tid;
        if (i < N) {
            float bf = rois[3 * i];
            if ((int)bf == b) {
                int pos = atomicAdd(&s_cnt, 1);
                s_idx[pos]   = i;
                s_start[pos] = rois[3 * i + 1];
                s_end[pos]   = rois[3 * i + 2];
            }
        }
    }
    __syncthreads();
    const int cnt = s_cnt;

    // --- Process: two 128-thread groups, one ROI each per iteration. ---
    const int g    = tid >> 7;        // 0,1
    const int t128 = tid & 127;
    const int c    = t128 >> 4;       // 0..7
    const int p    = t128 & 15;       // 0..15
    const float* trow = &tile[c * TSTRIDE];
    const int c_out = (ct * CTILE + c) * P_DIM + p;

    // Per-thread sample offsets: q[s] = p + (s+0.5)/4
    float qf[S_RAT];
#pragma unroll
    for (int s = 0; s < S_RAT; ++s)
        qf[s] = (float)p + ((float)s + 0.5f) * (1.0f / S_RAT);

#pragma unroll 2
    for (int i = g; i < cnt; i += 2) {
        const float start = s_start[i];
        const float bin   = fmaxf(s_end[i] - start, 1.0f) * (1.0f / P_DIM);

        float acc = 0.0f;
#pragma unroll
        for (int s = 0; s < S_RAT; ++s) {
            float x  = fmaf(qf[s], bin, start);       // x in [0, 512) by input construction
            float xc = fminf(x, (float)(T_DIM - 1));
            float tf = fminf(truncf(xc), (float)(T_DIM - 2));
            int   t  = (int)tf;
            float wh = (xc - tf) * (1.0f / S_RAT);
            float wl = (1.0f / S_RAT) - wh;
            acc = fmaf(trow[t], wl, fmaf(trow[t + 1], wh, acc));
        }
        // Wave lanes (c%4 | p) -> 64 consecutive floats: coalesced store.
        out[(size_t)s_idx[i] * (CH * P_DIM) + c_out] = acc;
    }
}

extern "C" void kernel_launch(void* const* d_in, const int* in_sizes, int n_in,
                              void* d_out, int out_size, void* d_ws, size_t ws_size,
                              hipStream_t stream) {
    const float* feat = (const float*)d_in[0];   // (8,256,512)
    const float* rois = (const float*)d_in[1];   // (N,3)
    float* out = (float*)d_out;                  // (N,256,16)
    const int N = in_sizes[1] / 3;               // 2048

    dim3 grid(NCT, RSPLIT, 8);                   // 2048 blocks
    roialign_lds_kernel<<<grid, dim3(256), 0, stream>>>(feat, rois, out, N);
}